// Round 12
// baseline (463.133 us; speedup 1.0000x reference)
//
#include <hip/hip_runtime.h>
#include <math.h>

#define HIDN 64
#define NCLS_K 32
#define INDIM 256
#define BSHIFT 7            // bucket = src >> 7  (128 src rows per bucket)
#define MAXBUCK 1024        // supports N <= 131072
#define BUCK_CAP 4096       // max edges per bucket (mean ~2046, max ~2350)
#define DSTBITS 17          // dst fits 17 bits; key = (local7<<17)|dst
#define DSTMASK ((1 << DSTBITS) - 1)
#define SCB 512             // scatter blocks (rank-based radix, no global atomics)

typedef unsigned int uint;
typedef unsigned short ushort;
typedef __attribute__((ext_vector_type(8))) short short8v;   // 8 bf16 (4 VGPR)
typedef __attribute__((ext_vector_type(4))) float f32x4;

__device__ inline ushort f2bf(float f) {               // round-to-nearest-even
  uint u = __float_as_uint(f);
  return (ushort)((u + 0x7FFFu + ((u >> 16) & 1u)) >> 16);
}
__device__ inline float bf2f(ushort h) { return __uint_as_float(((uint)h) << 16); }

// ---------------- per-node projections: pa = h.att_w[:64], pb = h.att_w[64:]
__global__ __launch_bounds__(256) void proj_kernel(const float* __restrict__ hid,
    const float* __restrict__ attw, float* __restrict__ pa, float* __restrict__ pb, int n) {
  int wid  = (blockIdx.x * blockDim.x + threadIdx.x) >> 6;
  int lane = threadIdx.x & 63;
  if (wid >= n) return;
  float v = hid[(size_t)wid * HIDN + lane];
  float a = v * attw[lane];
  float b = v * attw[HIDN + lane];
  #pragma unroll
  for (int off = 32; off >= 1; off >>= 1) {
    a += __shfl_xor(a, off, 64);
    b += __shfl_xor(b, off, 64);
  }
  if (lane == 0) { pa[wid] = a; pb[wid] = b; }
}

// ---------------- radix pass A: per-block histogram -> hmatT[bucket][block]
__global__ __launch_bounds__(256) void hist2(const int* __restrict__ src,
    int* __restrict__ hmatT, int e, int nb, int nper) {
  __shared__ int h[MAXBUCK];
  int lo = blockIdx.x * nper;
  int hi = min(e, lo + nper);
  for (int j = threadIdx.x; j < nb; j += 256) h[j] = 0;
  __syncthreads();
  for (int i = lo + threadIdx.x; i < hi; i += 256)
    atomicAdd(&h[src[i] >> BSHIFT], 1);
  __syncthreads();
  for (int j = threadIdx.x; j < nb; j += 256)
    hmatT[(size_t)j * SCB + blockIdx.x] = h[j];
}

// ---------------- radix pass B: per-bucket scan over SCB blocks (1 wave/bucket)
__global__ __launch_bounds__(256) void col_scan(int* __restrict__ hmatT,
    int* __restrict__ bcnt, int nb) {
  constexpr int PER = SCB / 64;            // 8 blocks per lane (contiguous chunk)
  int wv = blockIdx.x * 4 + (threadIdx.x >> 6);
  if (wv >= nb) return;
  int lane = threadIdx.x & 63;
  int* col = hmatT + (size_t)wv * SCB + lane * PER;
  int v[PER];
  int s = 0;
  #pragma unroll
  for (int q = 0; q < PER; ++q) { v[q] = col[q]; s += v[q]; }
  int x = s;                               // inclusive shuffle scan of chunk sums
  #pragma unroll
  for (int off = 1; off < 64; off <<= 1) {
    int t = __shfl_up(x, off, 64);
    if (lane >= off) x += t;
  }
  int pre = x - s;                         // exclusive chunk base
  #pragma unroll
  for (int q = 0; q < PER; ++q) { int t = v[q]; col[q] = pre; pre += t; }
  if (lane == 63) bcnt[wv] = pre;          // bucket total
}

// ---------------- CSR build: scan bucket totals (single block)
__global__ __launch_bounds__(1024) void scan_buckets(const int* __restrict__ bcnt,
    int* __restrict__ bbase, int* __restrict__ rowp, int nb, int n, int e) {
  __shared__ int sm[1024];
  int tid = threadIdx.x;
  int v = (tid < nb) ? bcnt[tid] : 0;
  sm[tid] = v;
  __syncthreads();
  for (int off = 1; off < 1024; off <<= 1) {
    int t = (tid >= off) ? sm[tid - off] : 0;
    __syncthreads();
    sm[tid] += t;
    __syncthreads();
  }
  if (tid < nb) bbase[tid] = sm[tid] - v;   // exclusive
  if (tid == 0) { bbase[nb] = e; rowp[n] = e; }
}

// ---------------- radix pass C: scatter into exclusive (block,bucket) regions
__global__ __launch_bounds__(256) void scatter2(const int* __restrict__ src,
    const int* __restrict__ dst, const int* __restrict__ hmatT,
    const int* __restrict__ bbase, int* __restrict__ pairs, int e, int nb, int nper) {
  __shared__ int h[MAXBUCK];
  int lo = blockIdx.x * nper;
  int hi = min(e, lo + nper);
  for (int j = threadIdx.x; j < nb; j += 256)
    h[j] = bbase[j] + hmatT[(size_t)j * SCB + blockIdx.x];
  __syncthreads();
  for (int i = lo + threadIdx.x; i < hi; i += 256) {
    int s = src[i];
    int pos = atomicAdd(&h[s >> BSHIFT], 1);
    pairs[pos] = ((s & 127) << DSTBITS) | dst[i];
  }
}

// ---------------- CSR build pass D: per-bucket LDS counting sort -> rowp, dstc
// dstc keeps the packed key: (local_row7 << 17) | dst  (spmm uses bits 17-20)
__global__ __launch_bounds__(256) void build_csr(const int* __restrict__ pairs,
    const int* __restrict__ bbase, int* __restrict__ rowp,
    int* __restrict__ dstc, int n) {
  __shared__ int hist[128];
  __shared__ int cur[128];
  __shared__ int ord[BUCK_CAP];
  int b = blockIdx.x;
  int tid = threadIdx.x;
  int base = bbase[b];
  int m = bbase[b + 1] - base;
  if (tid < 128) hist[tid] = 0;
  __syncthreads();
  for (int i = tid; i < m; i += 256)
    atomicAdd(&hist[pairs[base + i] >> DSTBITS], 1);
  __syncthreads();
  int own = (tid < 128) ? hist[tid] : 0;
  for (int off = 1; off < 128; off <<= 1) {          // inclusive scan of 128
    int t = (tid < 128 && tid >= off) ? hist[tid - off] : 0;
    __syncthreads();
    if (tid < 128) hist[tid] += t;
    __syncthreads();
  }
  if (tid < 128) {
    int excl = hist[tid] - own;
    cur[tid] = excl;
    int s = (b << BSHIFT) + tid;
    if (s < n) rowp[s] = base + excl;
  }
  __syncthreads();
  for (int i = tid; i < m; i += 256) {
    int key = pairs[base + i];
    int pos = atomicAdd(&cur[key >> DSTBITS], 1);
    ord[pos] = key;                                  // keep packed
  }
  __syncthreads();
  for (int i = tid; i < m; i += 256) dstc[base + i] = ord[i];
}

// in-wave 64-lane bitonic ascending sort of one key per lane
__device__ inline int wave_sort64(int key, int lane) {
  #pragma unroll
  for (int k = 2; k <= 64; k <<= 1) {
    #pragma unroll
    for (int j = k >> 1; j > 0; j >>= 1) {
      int p = __shfl_xor(key, j, 64);
      bool up    = ((lane & k) == 0);
      bool lower = ((lane & j) == 0);
      int mn = min(key, p), mx = max(key, p);
      key = (lower == up) ? mn : mx;
    }
  }
  return key;
}

// ---------------- per-row softmax, wave per row; sorts each row's dst list
// (keys stay packed; high bits row-constant so sort == dst sort). Writes bf16 att.
__global__ __launch_bounds__(256) void att_softmax(const float* __restrict__ pa,
    const float* __restrict__ pb, int* __restrict__ dstc,
    const int* __restrict__ rowp, ushort* __restrict__ attb, int n) {
  int wid  = (blockIdx.x * blockDim.x + threadIdx.x) >> 6;
  int lane = threadIdx.x & 63;
  if (wid >= n) return;
  int start = rowp[wid], end = rowp[wid + 1];
  int c = end - start;
  if (c <= 0) return;
  float pai = pa[wid];
  if (c <= 64) {                     // fast path: whole row in one wave
    int e = start + lane;
    int key = (lane < c) ? dstc[e] : 0x7FFFFFFF;
    key = wave_sort64(key, lane);
    float s = -3.0e38f;
    if (lane < c) {
      dstc[e] = key;
      float v = pai + pb[key & DSTMASK];
      s = v > 0.f ? v : 0.01f * v;
    }
    float m = s;
    #pragma unroll
    for (int off = 32; off >= 1; off >>= 1) m = fmaxf(m, __shfl_xor(m, off, 64));
    float ex = (lane < c) ? expf(s - m) : 0.f;
    float sum = ex;
    #pragma unroll
    for (int off = 32; off >= 1; off >>= 1) sum += __shfl_xor(sum, off, 64);
    if (lane < c) attb[e] = f2bf(ex / sum);
    return;
  }
  // slow path (statistically never at mean degree 16): bf16 scratch in attb
  float m = -3.0e38f;
  for (int base = start; base < end; base += 64) {
    int e = base + lane;
    int key = (e < end) ? dstc[e] : 0x7FFFFFFF;
    key = wave_sort64(key, lane);
    float s = -3.0e38f;
    if (e < end) {
      dstc[e] = key;
      float v = pai + pb[key & DSTMASK];
      s = v > 0.f ? v : 0.01f * v;
      attb[e] = f2bf(s);
    }
    m = fmaxf(m, s);
  }
  #pragma unroll
  for (int off = 32; off >= 1; off >>= 1) m = fmaxf(m, __shfl_xor(m, off, 64));
  float sum = 0.f;
  for (int base = start; base < end; base += 64) {
    int e = base + lane;
    float ex = 0.f;
    if (e < end) { ex = expf(bf2f(attb[e]) - m); attb[e] = f2bf(ex); }
    sum += ex;
  }
  #pragma unroll
  for (int off = 32; off >= 1; off >>= 1) sum += __shfl_xor(sum, off, 64);
  float inv = 1.f / sum;
  for (int base = start; base < end; base += 64) {
    int e = base + lane;
    if (e < end) attb[e] = f2bf(bf2f(attb[e]) * inv);
  }
}

// ---------------- jagged transpose: per 16-row group, permute edges from
// (row-major, dst-sorted) to (position-major): pos = C(j) + rank_j(row).
// Restores cross-wave dst-percentile correlation for the spmm gather window.
// In-place (wave-exclusive range); skip guard keeps correctness always.
__global__ __launch_bounds__(256) void reorder16(int* __restrict__ dstc,
    ushort* __restrict__ attb, const int* __restrict__ rowp, int n) {
  int g = blockIdx.x * 4 + (threadIdx.x >> 6);
  int row0 = g * 16;
  if (row0 >= n) return;
  int lane = threadIdx.x & 63;
  int nr = min(16, n - row0);
  int start = rowp[row0];
  int end   = rowp[row0 + nr];
  int m = end - start;
  if (m <= 0) return;
  int myd = (lane < nr) ? (rowp[row0 + lane + 1] - rowp[row0 + lane]) : 0;
  int maxd = myd;
  #pragma unroll
  for (int off = 32; off >= 1; off >>= 1) maxd = max(maxd, __shfl_xor(maxd, off, 64));
  if (maxd > 63 || m > 12 * 64) return;        // rare: keep original order
  int cnt = 0;                                  // cnt(j=lane) = #rows deg > j
  #pragma unroll
  for (int rr = 0; rr < 16; ++rr) cnt += (__shfl(myd, rr, 64) > lane) ? 1 : 0;
  int C = cnt;                                  // exclusive scan -> C(j)
  #pragma unroll
  for (int off = 1; off < 64; off <<= 1) {
    int t = __shfl_up(C, off, 64);
    if (lane >= off) C += t;
  }
  C -= cnt;
  int key[12]; ushort av[12]; int pos[12]; bool val[12];
  #pragma unroll
  for (int q = 0; q < 12; ++q) {
    int i = start + lane + q * 64;
    val[q] = (i < end);
    int ic = val[q] ? i : start;
    int k = dstc[ic];
    av[q] = attb[ic];
    int r = (k >> DSTBITS) & 15;
    int j = (ic - rowp[row0 + r]) & 63;
    int rank = 0;
    #pragma unroll
    for (int rp = 0; rp < 16; ++rp) {
      int drp = __shfl(myd, rp, 64);
      rank += (rp < r && drp > j) ? 1 : 0;
    }
    int Cj = __shfl(C, j, 64);
    key[q] = k;
    pos[q] = start + Cj + rank;
  }
  asm volatile("s_waitcnt vmcnt(0)" ::: "memory");   // all reads retired
  #pragma unroll
  for (int q = 0; q < 12; ++q) {
    if (val[q]) { dstc[pos[q]] = key[q]; attb[pos[q]] = av[q]; }
  }
}

// ---------------- MFMA GEMM: Xb[n x TJ](bf16) = A[n x K](f32) @ W[K x TJ](f32)
template <int K, int TJ>
__global__ __launch_bounds__(256) void gemm_mfma(const float* __restrict__ A,
    const float* __restrict__ W, ushort* __restrict__ Xb, int n) {
  constexpr int KP = K + 8;
  constexpr int NCB = TJ / 16;
  __shared__ ushort Wt[TJ][KP];
  const int tid = threadIdx.x;
  for (int idx = tid; idx < K * TJ; idx += 256) {
    int k = idx / TJ, j = idx % TJ;
    Wt[j][k] = f2bf(W[idx]);
  }
  __syncthreads();
  const int wv   = blockIdx.x * 4 + (tid >> 6);
  const int row0 = wv * 16;
  if (row0 >= n) return;
  const int lane = tid & 63;
  const int r    = lane & 15;
  const int kg   = lane >> 4;
  const int rowA = min(row0 + r, n - 1);
  const float* ap = A + (size_t)rowA * K + kg * 8;

  f32x4 acc[NCB];
  #pragma unroll
  for (int c = 0; c < NCB; ++c) acc[c] = (f32x4)(0.f);

  #pragma unroll
  for (int ks = 0; ks < K / 32; ++ks) {
    float4 a0 = *reinterpret_cast<const float4*>(ap + ks * 32);
    float4 a1 = *reinterpret_cast<const float4*>(ap + ks * 32 + 4);
    union { short8v v; ushort u[8]; } af;
    af.u[0] = f2bf(a0.x); af.u[1] = f2bf(a0.y);
    af.u[2] = f2bf(a0.z); af.u[3] = f2bf(a0.w);
    af.u[4] = f2bf(a1.x); af.u[5] = f2bf(a1.y);
    af.u[6] = f2bf(a1.z); af.u[7] = f2bf(a1.w);
    #pragma unroll
    for (int c = 0; c < NCB; ++c) {
      short8v bf = *reinterpret_cast<const short8v*>(&Wt[c * 16 + r][ks * 32 + kg * 8]);
      acc[c] = __builtin_amdgcn_mfma_f32_16x16x32_bf16(af.v, bf, acc[c], 0, 0, 0);
    }
  }
  #pragma unroll
  for (int c = 0; c < NCB; ++c) {
    #pragma unroll
    for (int i = 0; i < 4; ++i) {
      int rowS = row0 + kg * 4 + i;
      if (rowS < n) Xb[(size_t)rowS * TJ + c * 16 + r] = f2bf(acc[c][i]);
    }
  }
}

// ---------------- MFMA SpMM + ELU (+ fused log_softmax on final layer)
// Software-pipelined: window w+1's gathers issue while w does LDS+MFMA.
// Edge metadata (key,att) loaded once per window (2 loads) + shfl broadcast.
template <int TJ, bool FINAL>
__global__ __launch_bounds__(256) void spmm_mfma(const ushort* __restrict__ Xb,
    const ushort* __restrict__ attb, const int* __restrict__ dstc,
    const int* __restrict__ rowp, float* __restrict__ out, int n) {
  constexpr int NCB = TJ / 16;
  constexpr int CH  = TJ / 8;          // 16B chunks per row (8 or 4)
  constexpr int CHH = CH / 2;          // chunks staged per lane per window
  constexpr int EPP = 64 / CH;         // edge rows staged per pass
  constexpr int RS  = TJ + 4;          // LDS row stride (bank pad)
  __shared__ ushort Xs[4][32 * RS];
  const int tid   = threadIdx.x;
  const int wslot = tid >> 6;
  const int g     = blockIdx.x * 4 + wslot;
  const int row0  = g * 16;
  if (row0 >= n) return;
  const int lane = tid & 63;
  const int r    = lane & 15;
  const int kg   = lane >> 4;
  const int start = rowp[row0];
  const int end   = rowp[min(row0 + 16, n)];
  ushort* xs = Xs[wslot];
  const int cg  = lane % CH;
  const int ce  = lane / CH;
  const int l31 = lane & 31;

  f32x4 acc[NCB];
  #pragma unroll
  for (int c = 0; c < NCB; ++c) acc[c] = (f32x4)(0.f);

  // prologue: window 0 metadata + gathers
  int k32 = 0, a32 = 0;
  uint4 pre[CHH];
  if (start < end) {
    k32 = dstc[min(start + l31, end - 1)];
    a32 = (int)attb[min(start + l31, end - 1)];
    #pragma unroll
    for (int p = 0; p < CHH; ++p) {
      int el = p * EPP + ce;
      int d  = __shfl(k32, el, 64) & DSTMASK;
      pre[p] = *reinterpret_cast<const uint4*>(Xb + (size_t)d * TJ + cg * 8);
    }
  }
  for (int base = start; base < end; base += 32) {
    // issue next window's metadata + gathers (clamped on last window)
    int nb = (base + 32 < end) ? base + 32 : base;
    int nk = dstc[min(nb + l31, end - 1)];
    int na = (int)attb[min(nb + l31, end - 1)];
    uint4 nxt[CHH];
    #pragma unroll
    for (int p = 0; p < CHH; ++p) {
      int el = p * EPP + ce;
      int d  = __shfl(nk, el, 64) & DSTMASK;
      nxt[p] = *reinterpret_cast<const uint4*>(Xb + (size_t)d * TJ + cg * 8);
    }
    // stage current window's rows into LDS
    #pragma unroll
    for (int p = 0; p < CHH; ++p) {
      int el = p * EPP + ce;
      *reinterpret_cast<uint4*>(&xs[el * RS + cg * 8]) = pre[p];
    }
    // A fragment: att x (local-row == r) selector via shfl broadcast
    int sj = 8 * kg;
    union { short8v v; ushort u[8]; } af;
    #pragma unroll
    for (int j = 0; j < 8; ++j) {
      int kk = __shfl(k32, sj + j, 64);
      int aa = __shfl(a32, sj + j, 64);
      bool valid = (base + sj + j) < end;
      int rid = (kk >> DSTBITS) & 15;
      af.u[j] = (valid && rid == r) ? (ushort)aa : (ushort)0;
    }
    // B fragments from LDS + MFMA
    #pragma unroll
    for (int c = 0; c < NCB; ++c) {
      union { short8v v; ushort u[8]; } bf;
      #pragma unroll
      for (int i = 0; i < 8; ++i)
        bf.u[i] = xs[(8 * kg + i) * RS + c * 16 + r];
      acc[c] = __builtin_amdgcn_mfma_f32_16x16x32_bf16(af.v, bf.v, acc[c], 0, 0, 0);
    }
    k32 = nk; a32 = na;
    #pragma unroll
    for (int p = 0; p < CHH; ++p) pre[p] = nxt[p];
  }
  #pragma unroll
  for (int c = 0; c < NCB; ++c)
    #pragma unroll
    for (int i = 0; i < 4; ++i)
      acc[c][i] = acc[c][i] > 0.f ? acc[c][i] : (expf(acc[c][i]) - 1.f);  // ELU
  if (!FINAL) {
    #pragma unroll
    for (int c = 0; c < NCB; ++c)
      #pragma unroll
      for (int i = 0; i < 4; ++i) {
        int rowS = row0 + kg * 4 + i;
        if (rowS < n) out[(size_t)rowS * TJ + c * 16 + r] = acc[c][i];
      }
  } else {
    #pragma unroll
    for (int i = 0; i < 4; ++i) {
      float m = acc[0][i];
      #pragma unroll
      for (int c = 1; c < NCB; ++c) m = fmaxf(m, acc[c][i]);
      #pragma unroll
      for (int off = 1; off < 16; off <<= 1) m = fmaxf(m, __shfl_xor(m, off));
      float s = 0.f;
      #pragma unroll
      for (int c = 0; c < NCB; ++c) s += expf(acc[c][i] - m);
      #pragma unroll
      for (int off = 1; off < 16; off <<= 1) s += __shfl_xor(s, off);
      float lg = m + logf(s);
      int rowS = row0 + kg * 4 + i;
      if (rowS < n) {
        #pragma unroll
        for (int c = 0; c < NCB; ++c)
          out[(size_t)rowS * TJ + c * 16 + r] = acc[c][i] - lg;
      }
    }
  }
}

extern "C" void kernel_launch(void* const* d_in, const int* in_sizes, int n_in,
                              void* d_out, int out_size, void* d_ws, size_t ws_size,
                              hipStream_t stream) {
  const float* features = (const float*)d_in[0];
  const float* hidden   = (const float*)d_in[1];
  const int*   adj      = (const int*)d_in[2];
  const float* W0       = (const float*)d_in[3];
  const float* W1       = (const float*)d_in[4];
  const float* W2       = (const float*)d_in[5];
  const float* attw     = (const float*)d_in[6];
  float* out = (float*)d_out;

  const int N = in_sizes[1] / HIDN;   // 100000
  const int E = in_sizes[2] / 2;      // 1600000
  const int* src = adj;
  const int* dst = adj + E;
  const int NBUCK = (N + 127) >> BSHIFT;            // 782
  const int NB2   = ((NBUCK + 15) / 16) * 16;
  const int nper  = (E + SCB - 1) / SCB;

  // workspace layout — every segment 64B aligned
  int*   rowp  = (int*)d_ws;                        // N+16
  int*   bbase = rowp + (N + 16);                   // NB2+16
  int*   bcnt  = bbase + (NB2 + 16);                // NB2
  int*   hmatT = bcnt + NB2;                        // NBUCK*SCB (~1.6MB)
  int*   dstc  = hmatT + (size_t)NBUCK * SCB;       // E (packed keys)
  ushort* attb = (ushort*)(dstc + E);               // E bf16 (E/2 floats)
  float* Xf    = (float*)(attb) + (E / 2 + 16);     // N*64 floats reserved
  float* H     = Xf + (size_t)N * HIDN;             // N*64 floats
  ushort* Xb   = (ushort*)Xf;                       // bf16 X view
  int*   pairs = (int*)Xf;                          // E ints (dead before X write)
  float* pa    = H;                                 // N (dead before H written)
  float* pb    = H + N;                             // N

  dim3 blk(256);
  const int gridWave = (N + 3) / 4;
  const int gridG16  = ((N + 15) / 16 + 3) / 4;     // 4 waves/block, 16 rows/wave

  proj_kernel<<<gridWave, blk, 0, stream>>>(hidden, attw, pa, pb, N);
  hist2<<<SCB, blk, 0, stream>>>(src, hmatT, E, NBUCK, nper);
  col_scan<<<(NBUCK + 3) / 4, blk, 0, stream>>>(hmatT, bcnt, NBUCK);
  scan_buckets<<<1, 1024, 0, stream>>>(bcnt, bbase, rowp, NBUCK, N, E);
  scatter2<<<SCB, blk, 0, stream>>>(src, dst, hmatT, bbase, pairs, E, NBUCK, nper);
  build_csr<<<NBUCK, blk, 0, stream>>>(pairs, bbase, rowp, dstc, N);
  att_softmax<<<gridWave, blk, 0, stream>>>(pa, pb, dstc, rowp, attb, N);
  reorder16<<<gridG16, blk, 0, stream>>>(dstc, attb, rowp, N);

  gemm_mfma<INDIM, HIDN><<<gridG16, blk, 0, stream>>>(features, W0, Xb, N);
  spmm_mfma<HIDN, false><<<gridG16, blk, 0, stream>>>(Xb, attb, dstc, rowp, H, N);
  gemm_mfma<HIDN, HIDN><<<gridG16, blk, 0, stream>>>(H, W1, Xb, N);
  spmm_mfma<HIDN, false><<<gridG16, blk, 0, stream>>>(Xb, attb, dstc, rowp, H, N);
  gemm_mfma<HIDN, NCLS_K><<<gridG16, blk, 0, stream>>>(H, W2, Xb, N);
  spmm_mfma<NCLS_K, true><<<gridG16, blk, 0, stream>>>(Xb, attb, dstc, rowp, out, N);
}

// Round 13
// 294.130 us; speedup vs baseline: 1.5746x; 1.5746x over previous
//
#include <hip/hip_runtime.h>
#include <math.h>

#define HIDN 64
#define NCLS_K 32
#define INDIM 256
#define BSHIFT 7            // bucket = src >> 7  (128 src rows per bucket)
#define MAXBUCK 1024        // supports N <= 131072
#define BUCK_CAP 4096       // max edges per bucket (mean ~2046, max ~2350)
#define DSTBITS 17          // dst fits 17 bits; key = (local7<<17)|dst
#define DSTMASK ((1 << DSTBITS) - 1)
#define SCB 512             // scatter blocks (rank-based radix, no global atomics)

typedef unsigned int uint;
typedef unsigned short ushort;
typedef __attribute__((ext_vector_type(8))) short short8v;   // 8 bf16 (4 VGPR)
typedef __attribute__((ext_vector_type(4))) float f32x4;

__device__ inline ushort f2bf(float f) {               // round-to-nearest-even
  uint u = __float_as_uint(f);
  return (ushort)((u + 0x7FFFu + ((u >> 16) & 1u)) >> 16);
}
__device__ inline float bf2f(ushort h) { return __uint_as_float(((uint)h) << 16); }

// ---------------- per-node projections: pa = h.att_w[:64], pb = h.att_w[64:]
__global__ __launch_bounds__(256) void proj_kernel(const float* __restrict__ hid,
    const float* __restrict__ attw, float* __restrict__ pa, float* __restrict__ pb, int n) {
  int wid  = (blockIdx.x * blockDim.x + threadIdx.x) >> 6;
  int lane = threadIdx.x & 63;
  if (wid >= n) return;
  float v = hid[(size_t)wid * HIDN + lane];
  float a = v * attw[lane];
  float b = v * attw[HIDN + lane];
  #pragma unroll
  for (int off = 32; off >= 1; off >>= 1) {
    a += __shfl_xor(a, off, 64);
    b += __shfl_xor(b, off, 64);
  }
  if (lane == 0) { pa[wid] = a; pb[wid] = b; }
}

// ---------------- radix pass A: per-block histogram -> hmatT[bucket][block]
__global__ __launch_bounds__(256) void hist2(const int* __restrict__ src,
    int* __restrict__ hmatT, int e, int nb, int nper) {
  __shared__ int h[MAXBUCK];
  int lo = blockIdx.x * nper;
  int hi = min(e, lo + nper);
  for (int j = threadIdx.x; j < nb; j += 256) h[j] = 0;
  __syncthreads();
  for (int i = lo + threadIdx.x; i < hi; i += 256)
    atomicAdd(&h[src[i] >> BSHIFT], 1);
  __syncthreads();
  for (int j = threadIdx.x; j < nb; j += 256)
    hmatT[(size_t)j * SCB + blockIdx.x] = h[j];
}

// ---------------- radix pass B: per-bucket scan over SCB blocks (1 wave/bucket)
__global__ __launch_bounds__(256) void col_scan(int* __restrict__ hmatT,
    int* __restrict__ bcnt, int nb) {
  constexpr int PER = SCB / 64;            // 8 blocks per lane (contiguous chunk)
  int wv = blockIdx.x * 4 + (threadIdx.x >> 6);
  if (wv >= nb) return;
  int lane = threadIdx.x & 63;
  int* col = hmatT + (size_t)wv * SCB + lane * PER;
  int v[PER];
  int s = 0;
  #pragma unroll
  for (int q = 0; q < PER; ++q) { v[q] = col[q]; s += v[q]; }
  int x = s;                               // inclusive shuffle scan of chunk sums
  #pragma unroll
  for (int off = 1; off < 64; off <<= 1) {
    int t = __shfl_up(x, off, 64);
    if (lane >= off) x += t;
  }
  int pre = x - s;                         // exclusive chunk base
  #pragma unroll
  for (int q = 0; q < PER; ++q) { int t = v[q]; col[q] = pre; pre += t; }
  if (lane == 63) bcnt[wv] = pre;          // bucket total
}

// ---------------- CSR build: scan bucket totals (single block)
__global__ __launch_bounds__(1024) void scan_buckets(const int* __restrict__ bcnt,
    int* __restrict__ bbase, int* __restrict__ rowp, int nb, int n, int e) {
  __shared__ int sm[1024];
  int tid = threadIdx.x;
  int v = (tid < nb) ? bcnt[tid] : 0;
  sm[tid] = v;
  __syncthreads();
  for (int off = 1; off < 1024; off <<= 1) {
    int t = (tid >= off) ? sm[tid - off] : 0;
    __syncthreads();
    sm[tid] += t;
    __syncthreads();
  }
  if (tid < nb) bbase[tid] = sm[tid] - v;   // exclusive
  if (tid == 0) { bbase[nb] = e; rowp[n] = e; }
}

// ---------------- radix pass C: scatter into exclusive (block,bucket) regions
__global__ __launch_bounds__(256) void scatter2(const int* __restrict__ src,
    const int* __restrict__ dst, const int* __restrict__ hmatT,
    const int* __restrict__ bbase, int* __restrict__ pairs, int e, int nb, int nper) {
  __shared__ int h[MAXBUCK];
  int lo = blockIdx.x * nper;
  int hi = min(e, lo + nper);
  for (int j = threadIdx.x; j < nb; j += 256)
    h[j] = bbase[j] + hmatT[(size_t)j * SCB + blockIdx.x];
  __syncthreads();
  for (int i = lo + threadIdx.x; i < hi; i += 256) {
    int s = src[i];
    int pos = atomicAdd(&h[s >> BSHIFT], 1);
    pairs[pos] = ((s & 127) << DSTBITS) | dst[i];
  }
}

// ---------------- CSR build pass D: per-bucket LDS counting sort -> rowp, dstc
// dstc keeps the packed key: (local_row7 << 17) | dst  (spmm uses bits 17-20)
__global__ __launch_bounds__(256) void build_csr(const int* __restrict__ pairs,
    const int* __restrict__ bbase, int* __restrict__ rowp,
    int* __restrict__ dstc, int n) {
  __shared__ int hist[128];
  __shared__ int cur[128];
  __shared__ int ord[BUCK_CAP];
  int b = blockIdx.x;
  int tid = threadIdx.x;
  int base = bbase[b];
  int m = bbase[b + 1] - base;
  if (tid < 128) hist[tid] = 0;
  __syncthreads();
  for (int i = tid; i < m; i += 256)
    atomicAdd(&hist[pairs[base + i] >> DSTBITS], 1);
  __syncthreads();
  int own = (tid < 128) ? hist[tid] : 0;
  for (int off = 1; off < 128; off <<= 1) {          // inclusive scan of 128
    int t = (tid < 128 && tid >= off) ? hist[tid - off] : 0;
    __syncthreads();
    if (tid < 128) hist[tid] += t;
    __syncthreads();
  }
  if (tid < 128) {
    int excl = hist[tid] - own;
    cur[tid] = excl;
    int s = (b << BSHIFT) + tid;
    if (s < n) rowp[s] = base + excl;
  }
  __syncthreads();
  for (int i = tid; i < m; i += 256) {
    int key = pairs[base + i];
    int pos = atomicAdd(&cur[key >> DSTBITS], 1);
    ord[pos] = key;                                  // keep packed
  }
  __syncthreads();
  for (int i = tid; i < m; i += 256) dstc[base + i] = ord[i];
}

// in-wave 64-lane bitonic ascending sort of one key per lane
__device__ inline int wave_sort64(int key, int lane) {
  #pragma unroll
  for (int k = 2; k <= 64; k <<= 1) {
    #pragma unroll
    for (int j = k >> 1; j > 0; j >>= 1) {
      int p = __shfl_xor(key, j, 64);
      bool up    = ((lane & k) == 0);
      bool lower = ((lane & j) == 0);
      int mn = min(key, p), mx = max(key, p);
      key = (lower == up) ? mn : mx;
    }
  }
  return key;
}

// ---------------- per-row softmax, wave per row; sorts each row's dst list
// (keys stay packed; high bits row-constant so sort == dst sort). Writes bf16 att.
__global__ __launch_bounds__(256) void att_softmax(const float* __restrict__ pa,
    const float* __restrict__ pb, int* __restrict__ dstc,
    const int* __restrict__ rowp, ushort* __restrict__ attb, int n) {
  int wid  = (blockIdx.x * blockDim.x + threadIdx.x) >> 6;
  int lane = threadIdx.x & 63;
  if (wid >= n) return;
  int start = rowp[wid], end = rowp[wid + 1];
  int c = end - start;
  if (c <= 0) return;
  float pai = pa[wid];
  if (c <= 64) {                     // fast path: whole row in one wave
    int e = start + lane;
    int key = (lane < c) ? dstc[e] : 0x7FFFFFFF;
    key = wave_sort64(key, lane);
    float s = -3.0e38f;
    if (lane < c) {
      dstc[e] = key;
      float v = pai + pb[key & DSTMASK];
      s = v > 0.f ? v : 0.01f * v;
    }
    float m = s;
    #pragma unroll
    for (int off = 32; off >= 1; off >>= 1) m = fmaxf(m, __shfl_xor(m, off, 64));
    float ex = (lane < c) ? expf(s - m) : 0.f;
    float sum = ex;
    #pragma unroll
    for (int off = 32; off >= 1; off >>= 1) sum += __shfl_xor(sum, off, 64);
    if (lane < c) attb[e] = f2bf(ex / sum);
    return;
  }
  // slow path (statistically never at mean degree 16): bf16 scratch in attb
  float m = -3.0e38f;
  for (int base = start; base < end; base += 64) {
    int e = base + lane;
    int key = (e < end) ? dstc[e] : 0x7FFFFFFF;
    key = wave_sort64(key, lane);
    float s = -3.0e38f;
    if (e < end) {
      dstc[e] = key;
      float v = pai + pb[key & DSTMASK];
      s = v > 0.f ? v : 0.01f * v;
      attb[e] = f2bf(s);
    }
    m = fmaxf(m, s);
  }
  #pragma unroll
  for (int off = 32; off >= 1; off >>= 1) m = fmaxf(m, __shfl_xor(m, off, 64));
  float sum = 0.f;
  for (int base = start; base < end; base += 64) {
    int e = base + lane;
    float ex = 0.f;
    if (e < end) { ex = expf(bf2f(attb[e]) - m); attb[e] = f2bf(ex); }
    sum += ex;
  }
  #pragma unroll
  for (int off = 32; off >= 1; off >>= 1) sum += __shfl_xor(sum, off, 64);
  float inv = 1.f / sum;
  for (int base = start; base < end; base += 64) {
    int e = base + lane;
    if (e < end) attb[e] = f2bf(bf2f(attb[e]) * inv);
  }
}

// ---------------- jagged transpose: per 16-row group, permute edges from
// (row-major, dst-sorted) to (position-major): pos = C(j) + rank_j(row).
// Restores cross-wave dst-percentile correlation for the spmm gather window.
// In-place (wave-exclusive range); skip guard keeps correctness always.
__global__ __launch_bounds__(256) void reorder16(int* __restrict__ dstc,
    ushort* __restrict__ attb, const int* __restrict__ rowp, int n) {
  int g = blockIdx.x * 4 + (threadIdx.x >> 6);
  int row0 = g * 16;
  if (row0 >= n) return;
  int lane = threadIdx.x & 63;
  int nr = min(16, n - row0);
  int start = rowp[row0];
  int end   = rowp[row0 + nr];
  int m = end - start;
  if (m <= 0) return;
  int myd = (lane < nr) ? (rowp[row0 + lane + 1] - rowp[row0 + lane]) : 0;
  int maxd = myd;
  #pragma unroll
  for (int off = 32; off >= 1; off >>= 1) maxd = max(maxd, __shfl_xor(maxd, off, 64));
  if (maxd > 63 || m > 12 * 64) return;        // rare: keep original order
  int cnt = 0;                                  // cnt(j=lane) = #rows deg > j
  #pragma unroll
  for (int rr = 0; rr < 16; ++rr) cnt += (__shfl(myd, rr, 64) > lane) ? 1 : 0;
  int C = cnt;                                  // exclusive scan -> C(j)
  #pragma unroll
  for (int off = 1; off < 64; off <<= 1) {
    int t = __shfl_up(C, off, 64);
    if (lane >= off) C += t;
  }
  C -= cnt;
  int key[12]; ushort av[12]; int pos[12]; bool val[12];
  #pragma unroll
  for (int q = 0; q < 12; ++q) {
    int i = start + lane + q * 64;
    val[q] = (i < end);
    int ic = val[q] ? i : start;
    int k = dstc[ic];
    av[q] = attb[ic];
    int r = (k >> DSTBITS) & 15;
    int j = (ic - rowp[row0 + r]) & 63;
    int rank = 0;
    #pragma unroll
    for (int rp = 0; rp < 16; ++rp) {
      int drp = __shfl(myd, rp, 64);
      rank += (rp < r && drp > j) ? 1 : 0;
    }
    int Cj = __shfl(C, j, 64);
    key[q] = k;
    pos[q] = start + Cj + rank;
  }
  asm volatile("s_waitcnt vmcnt(0)" ::: "memory");   // all reads retired
  #pragma unroll
  for (int q = 0; q < 12; ++q) {
    if (val[q]) { dstc[pos[q]] = key[q]; attb[pos[q]] = av[q]; }
  }
}

// ---------------- MFMA GEMM: Xb[n x TJ](bf16) = A[n x K](f32) @ W[K x TJ](f32)
template <int K, int TJ>
__global__ __launch_bounds__(256) void gemm_mfma(const float* __restrict__ A,
    const float* __restrict__ W, ushort* __restrict__ Xb, int n) {
  constexpr int KP = K + 8;
  constexpr int NCB = TJ / 16;
  __shared__ ushort Wt[TJ][KP];
  const int tid = threadIdx.x;
  for (int idx = tid; idx < K * TJ; idx += 256) {
    int k = idx / TJ, j = idx % TJ;
    Wt[j][k] = f2bf(W[idx]);
  }
  __syncthreads();
  const int wv   = blockIdx.x * 4 + (tid >> 6);
  const int row0 = wv * 16;
  if (row0 >= n) return;
  const int lane = tid & 63;
  const int r    = lane & 15;
  const int kg   = lane >> 4;
  const int rowA = min(row0 + r, n - 1);
  const float* ap = A + (size_t)rowA * K + kg * 8;

  f32x4 acc[NCB];
  #pragma unroll
  for (int c = 0; c < NCB; ++c) acc[c] = (f32x4)(0.f);

  #pragma unroll
  for (int ks = 0; ks < K / 32; ++ks) {
    float4 a0 = *reinterpret_cast<const float4*>(ap + ks * 32);
    float4 a1 = *reinterpret_cast<const float4*>(ap + ks * 32 + 4);
    union { short8v v; ushort u[8]; } af;
    af.u[0] = f2bf(a0.x); af.u[1] = f2bf(a0.y);
    af.u[2] = f2bf(a0.z); af.u[3] = f2bf(a0.w);
    af.u[4] = f2bf(a1.x); af.u[5] = f2bf(a1.y);
    af.u[6] = f2bf(a1.z); af.u[7] = f2bf(a1.w);
    #pragma unroll
    for (int c = 0; c < NCB; ++c) {
      short8v bf = *reinterpret_cast<const short8v*>(&Wt[c * 16 + r][ks * 32 + kg * 8]);
      acc[c] = __builtin_amdgcn_mfma_f32_16x16x32_bf16(af.v, bf, acc[c], 0, 0, 0);
    }
  }
  #pragma unroll
  for (int c = 0; c < NCB; ++c) {
    #pragma unroll
    for (int i = 0; i < 4; ++i) {
      int rowS = row0 + kg * 4 + i;
      if (rowS < n) Xb[(size_t)rowS * TJ + c * 16 + r] = f2bf(acc[c][i]);
    }
  }
}

// ---------------- MFMA SpMM + ELU (+ fused log_softmax on final layer)
// R11 version (no software pipeline — that spilled to scratch in R12).
// Per 32-edge window: stage gathered rows via coalesced 16B/lane uint4 loads
// into wave-private LDS [32][TJ+4], then feed B-fragments to MFMA from LDS.
template <int TJ, bool FINAL>
__global__ __launch_bounds__(256) void spmm_mfma(const ushort* __restrict__ Xb,
    const ushort* __restrict__ attb, const int* __restrict__ dstc,
    const int* __restrict__ rowp, float* __restrict__ out, int n) {
  constexpr int NCB = TJ / 16;
  constexpr int CH  = TJ / 8;          // 16B chunks per row (8 or 4)
  constexpr int EPP = 64 / CH;         // edge rows staged per pass (8 or 16)
  constexpr int RS  = TJ + 4;          // LDS row stride in elements (bank pad)
  __shared__ ushort Xs[4][32 * RS];
  const int tid   = threadIdx.x;
  const int wslot = tid >> 6;
  const int g     = blockIdx.x * 4 + wslot;    // wave id = 16-row group
  const int row0  = g * 16;
  if (row0 >= n) return;
  const int lane = tid & 63;
  const int r    = lane & 15;
  const int kg   = lane >> 4;
  const int start = rowp[row0];
  const int end   = rowp[min(row0 + 16, n)];
  ushort* xs = Xs[wslot];
  const int cg = lane % CH;            // staging chunk id
  const int ce = lane / CH;            // staging edge-sub

  f32x4 acc[NCB];
  #pragma unroll
  for (int c = 0; c < NCB; ++c) acc[c] = (f32x4)(0.f);

  for (int base = start; base < end; base += 32) {
    // 1) stage 32 edge rows into LDS (dense 16B/lane gathers)
    #pragma unroll
    for (int p = 0; p < CH / 2; ++p) {
      int el  = p * EPP + ce;
      int idx = min(base + el, end - 1);
      int d   = dstc[idx] & DSTMASK;
      uint4 u = *reinterpret_cast<const uint4*>(Xb + (size_t)d * TJ + cg * 8);
      *reinterpret_cast<uint4*>(&xs[el * RS + cg * 8]) = u;
    }
    // 2) A-fragment: att x (local-row == r) selector, k = 8*kg + j
    int sbase = base + 8 * kg;
    union { short8v v; ushort u[8]; } af;
    #pragma unroll
    for (int j = 0; j < 8; ++j) {
      int e = sbase + j;
      bool valid = e < end;
      int idx = valid ? e : (end - 1);
      int v = dstc[idx];
      ushort a = attb[idx];
      int rid = (v >> DSTBITS) & 15;
      af.u[j] = (valid && rid == r) ? a : (ushort)0;
    }
    // 3) B-fragments from LDS + MFMA
    #pragma unroll
    for (int c = 0; c < NCB; ++c) {
      union { short8v v; ushort u[8]; } bf;
      #pragma unroll
      for (int i = 0; i < 8; ++i)
        bf.u[i] = xs[(8 * kg + i) * RS + c * 16 + r];
      acc[c] = __builtin_amdgcn_mfma_f32_16x16x32_bf16(af.v, bf.v, acc[c], 0, 0, 0);
    }
  }
  #pragma unroll
  for (int c = 0; c < NCB; ++c)
    #pragma unroll
    for (int i = 0; i < 4; ++i)
      acc[c][i] = acc[c][i] > 0.f ? acc[c][i] : (expf(acc[c][i]) - 1.f);  // ELU
  if (!FINAL) {
    #pragma unroll
    for (int c = 0; c < NCB; ++c)
      #pragma unroll
      for (int i = 0; i < 4; ++i) {
        int rowS = row0 + kg * 4 + i;
        if (rowS < n) out[(size_t)rowS * TJ + c * 16 + r] = acc[c][i];
      }
  } else {
    #pragma unroll
    for (int i = 0; i < 4; ++i) {
      float m = acc[0][i];
      #pragma unroll
      for (int c = 1; c < NCB; ++c) m = fmaxf(m, acc[c][i]);
      #pragma unroll
      for (int off = 1; off < 16; off <<= 1) m = fmaxf(m, __shfl_xor(m, off));
      float s = 0.f;
      #pragma unroll
      for (int c = 0; c < NCB; ++c) s += expf(acc[c][i] - m);
      #pragma unroll
      for (int off = 1; off < 16; off <<= 1) s += __shfl_xor(s, off);
      float lg = m + logf(s);
      int rowS = row0 + kg * 4 + i;
      if (rowS < n) {
        #pragma unroll
        for (int c = 0; c < NCB; ++c)
          out[(size_t)rowS * TJ + c * 16 + r] = acc[c][i] - lg;
      }
    }
  }
}

extern "C" void kernel_launch(void* const* d_in, const int* in_sizes, int n_in,
                              void* d_out, int out_size, void* d_ws, size_t ws_size,
                              hipStream_t stream) {
  const float* features = (const float*)d_in[0];
  const float* hidden   = (const float*)d_in[1];
  const int*   adj      = (const int*)d_in[2];
  const float* W0       = (const float*)d_in[3];
  const float* W1       = (const float*)d_in[4];
  const float* W2       = (const float*)d_in[5];
  const float* attw     = (const float*)d_in[6];
  float* out = (float*)d_out;

  const int N = in_sizes[1] / HIDN;   // 100000
  const int E = in_sizes[2] / 2;      // 1600000
  const int* src = adj;
  const int* dst = adj + E;
  const int NBUCK = (N + 127) >> BSHIFT;            // 782
  const int NB2   = ((NBUCK + 15) / 16) * 16;
  const int nper  = (E + SCB - 1) / SCB;

  // workspace layout — every segment 64B aligned
  int*   rowp  = (int*)d_ws;                        // N+16
  int*   bbase = rowp + (N + 16);                   // NB2+16
  int*   bcnt  = bbase + (NB2 + 16);                // NB2
  int*   hmatT = bcnt + NB2;                        // NBUCK*SCB (~1.6MB)
  int*   dstc  = hmatT + (size_t)NBUCK * SCB;       // E (packed keys)
  ushort* attb = (ushort*)(dstc + E);               // E bf16 (E/2 floats)
  float* Xf    = (float*)(attb) + (E / 2 + 16);     // N*64 floats reserved
  float* H     = Xf + (size_t)N * HIDN;             // N*64 floats
  ushort* Xb   = (ushort*)Xf;                       // bf16 X view
  int*   pairs = (int*)Xf;                          // E ints (dead before X write)
  float* pa    = H;                                 // N (dead before H written)
  float* pb    = H + N;                             // N

  dim3 blk(256);
  const int gridWave = (N + 3) / 4;
  const int gridG16  = ((N + 15) / 16 + 3) / 4;     // 4 waves/block, 16 rows/wave

  proj_kernel<<<gridWave, blk, 0, stream>>>(hidden, attw, pa, pb, N);
  hist2<<<SCB, blk, 0, stream>>>(src, hmatT, E, NBUCK, nper);
  col_scan<<<(NBUCK + 3) / 4, blk, 0, stream>>>(hmatT, bcnt, NBUCK);
  scan_buckets<<<1, 1024, 0, stream>>>(bcnt, bbase, rowp, NBUCK, N, E);
  scatter2<<<SCB, blk, 0, stream>>>(src, dst, hmatT, bbase, pairs, E, NBUCK, nper);
  build_csr<<<NBUCK, blk, 0, stream>>>(pairs, bbase, rowp, dstc, N);
  att_softmax<<<gridWave, blk, 0, stream>>>(pa, pb, dstc, rowp, attb, N);
  reorder16<<<gridG16, blk, 0, stream>>>(dstc, attb, rowp, N);

  gemm_mfma<INDIM, HIDN><<<gridG16, blk, 0, stream>>>(features, W0, Xb, N);
  spmm_mfma<HIDN, false><<<gridG16, blk, 0, stream>>>(Xb, attb, dstc, rowp, H, N);
  gemm_mfma<HIDN, HIDN><<<gridG16, blk, 0, stream>>>(H, W1, Xb, N);
  spmm_mfma<HIDN, false><<<gridG16, blk, 0, stream>>>(Xb, attb, dstc, rowp, H, N);
  gemm_mfma<HIDN, NCLS_K><<<gridG16, blk, 0, stream>>>(H, W2, Xb, N);
  spmm_mfma<NCLS_K, true><<<gridG16, blk, 0, stream>>>(Xb, attb, dstc, rowp, out, N);
}